// Round 6
// baseline (710.144 us; speedup 1.0000x reference)
//
#include <hip/hip_runtime.h>
#include <stdint.h>

// Problem constants: x[16,64,256,256] fp32, W[1024,1024] fp32, P=4.
// GEMM view: C[m,n] = sum_k A[m,k] * W[n,k]
//   m = b*4096 + hp*64 + wp   (Hp=Wp=64)
//   k = c*16 + ph*4 + pw
// Tiling: BM=128, BN=64, BK=32, 32 K-iters. Grid 512 mt x 16 nt = 8192.
//
// Round-6: same verified A path as round 5 (LDS-staged, XOR-skewed,
// 2 raw barriers/iter with lgkm-only drain; B from pre-packed bf16 table
// Wp[kq][n] in d_ws). Change: BN 128->64 so each wave's accumulator is
// acc[4][2] = 32 AGPR instead of 64. Total regs/wave ~88 < 102 ->
// 5 waves/SIMD (62.5% occupancy) vs the previous hard cap of 4 (50%).
// Rationale: measured T_iter ~5000 cyc vs ~310 cyc of MFMA work/wave-iter
// with all pipes <20% busy = TLP shortage, and occupancy elasticity ~1
// (rounds 2/3). Cost: A staged by 16 n-blocks instead of 8 (staging proved
// cheap in rounds 1->5; A strip stays L2-resident under the XCD swizzle).

typedef float    f32x4  __attribute__((ext_vector_type(4)));
typedef uint32_t u32x4  __attribute__((ext_vector_type(4)));
typedef __bf16   bf16x8 __attribute__((ext_vector_type(8)));

// Truncate two f32 to bf16 and pack into one u32 (lo in low half).
__device__ __forceinline__ uint32_t pack2(float lo, float hi) {
    return __builtin_amdgcn_perm(__builtin_bit_cast(uint32_t, hi),
                                 __builtin_bit_cast(uint32_t, lo),
                                 0x07060302u);
}

// ---- W prep: W[n][k] fp32 -> Wp granule[kq][n] = 8 bf16 {k=kq*8..kq*8+7} ----
// 128k granules total (kq 0..127, n 0..1023) = 2 MB.
__global__ __launch_bounds__(256)
void wprep_kernel(const float* __restrict__ Wm, u32x4* __restrict__ Wp) {
    const int t  = blockIdx.x * 256 + threadIdx.x;   // 0..131071
    if (t >= 128 * 1024) return;
    const int n  = t & 1023;                          // write-coalesced in n
    const int kq = t >> 10;                           // 0..127
    const float* src = Wm + (size_t)n * 1024 + (size_t)kq * 8;
    f32x4 lo = *(const f32x4*)(src);
    f32x4 hi = *(const f32x4*)(src + 4);
    Wp[(size_t)kq * 1024 + n] = (u32x4){ pack2(lo.x, lo.y), pack2(lo.z, lo.w),
                                         pack2(hi.x, hi.y), pack2(hi.z, hi.w) };
}

__global__ __launch_bounds__(256, 5)
void patchmix_kernel(const float* __restrict__ x,
                     const u32x4* __restrict__ Wp,
                     float* __restrict__ y) {
    // ---- XCD-aware block swizzle (T1): contiguous M-chunk per XCD, N fastest.
    // 8192 % 8 == 0 -> bijective.
    const int bx  = blockIdx.x;
    const int xcd = bx & 7;
    const int jj  = bx >> 3;       // 0..1023 within this XCD
    const int nt  = jj & 15;       // N-tile fastest -> A-strip L2 reuse (16x)
    const int mt  = xcd * 64 + (jj >> 4);   // 0..511
    const int bb  = mt >> 5;       // batch 0..15
    const int hp0 = (mt & 31) << 1;// first of 2 hp rows
    const int n0  = nt << 6;       // 64-wide N tile

    const int t    = threadIdx.x;
    const int lane = t & 63;
    const int wave = t >> 6;
    const int wm   = wave >> 1;    // wave row in 2x2 grid (64-row half)
    const int wn   = wave & 1;     // wave col (32-n half)

    // A tile only: [kq(0..3)][rowS(0..127)] of u32x4 = 8 KB single buffer.
    // XOR skew (row ^ (kq<<1)): bank-conflict-free (verified: 0 conflicts).
    __shared__ u32x4 Alds[4 * 128];

    // ---- A staging geometry (round-1/5 verbatim) ----
    const int hpL = (wave >> 1) & 1;
    const int phh = wave & 1;
    const float* aBase0 = x + (size_t)bb * (64 * 256 * 256)
                            + ((size_t)(hp0 + hpL) * 4 + 2 * phh) * 256 + lane * 4;
    const int aM = hpL * 64 + lane;          // LDS row (= m_local)
    const int kqA0 = phh,     kqA1 = 2 + phh;
    const int aM0  = aM ^ (kqA0 << 1);
    const int aM1  = aM ^ (kqA1 << 1);

    const int kg  = lane >> 4;   // k-group 0..3
    const int lr  = lane & 15;
    const int lrS = lr ^ (kg << 1);

    // B fragment pointer: granule (it*4+kg)*1024 + (n0 + wn*32 + j*16 + lr)
    const u32x4* bFrag = Wp + (size_t)kg * 1024 + (size_t)(n0 + wn * 32 + lr);

    f32x4 aR[2][2];
    auto loadA = [&](int it) {
        const float* a0 = aBase0 + (size_t)(it * 2) * 65536;
        aR[0][0] = *(const f32x4*)(a0);
        aR[0][1] = *(const f32x4*)(a0 + 256);
        aR[1][0] = *(const f32x4*)(a0 + 65536);
        aR[1][1] = *(const f32x4*)(a0 + 65536 + 256);
    };

    f32x4 acc[4][2];
    #pragma unroll
    for (int i = 0; i < 4; ++i)
        #pragma unroll
        for (int j = 0; j < 2; ++j)
            acc[i][j] = (f32x4){0.f, 0.f, 0.f, 0.f};

    loadA(0);

    #pragma unroll 1
    for (int it = 0; it < 32; ++it) {
        // 1. pack A(it) -> bf16 (waits on aR loads; slack = full prev iter)
        u32x4 apk0 = (u32x4){ pack2(aR[0][0].x, aR[0][0].y), pack2(aR[0][0].z, aR[0][0].w),
                              pack2(aR[0][1].x, aR[0][1].y), pack2(aR[0][1].z, aR[0][1].w) };
        u32x4 apk1 = (u32x4){ pack2(aR[1][0].x, aR[1][0].y), pack2(aR[1][0].z, aR[1][0].w),
                              pack2(aR[1][1].x, aR[1][1].y), pack2(aR[1][1].z, aR[1][1].w) };
        // 2. issue B fragments for this iter (bf16, L2-resident, no pack)
        bf16x8 bfr[2];
        {
            const u32x4* bi = bFrag + (size_t)it * 4096;
            #pragma unroll
            for (int j = 0; j < 2; ++j)
                bfr[j] = __builtin_bit_cast(bf16x8, bi[j * 16]);
        }
        // 3. prefetch A(it+1): stays in flight across both barriers
        if (it + 1 < 32) loadA(it + 1);
        // 4. bar1: all waves done reading Alds tile it-1 (lgkm-only drain;
        //    global prefetch NOT drained)
        asm volatile("s_waitcnt lgkmcnt(0)" ::: "memory");
        __builtin_amdgcn_s_barrier();
        asm volatile("" ::: "memory");
        // 5. write A(it)
        Alds[kqA0 * 128 + aM0] = apk0;
        Alds[kqA1 * 128 + aM1] = apk1;
        // 6. bar2: tile it visible
        asm volatile("s_waitcnt lgkmcnt(0)" ::: "memory");
        __builtin_amdgcn_s_barrier();
        asm volatile("" ::: "memory");
        // 7. read A fragments + MFMA
        bf16x8 af[4];
        #pragma unroll
        for (int i = 0; i < 4; ++i)
            af[i] = __builtin_bit_cast(bf16x8, Alds[kg * 128 + wm * 64 + i * 16 + lrS]);
        #pragma unroll
        for (int i = 0; i < 4; ++i)
            #pragma unroll
            for (int j = 0; j < 2; ++j)
                acc[i][j] = __builtin_amdgcn_mfma_f32_16x16x32_bf16(
                                af[i], bfr[j], acc[i][j], 0, 0, 0);
    }

    // ---- epilogue: fold back to y[b][c][h][w] ----
    // D layout (m89): col n = lane&15, row m = (lane>>4)*4 + reg
    // m_local = wm*64 + i*16 + kg*4 + r  ->  hpL = wm, wp = i*16 + kg*4 + r
    float* yb = y + (size_t)bb * (64 * 256 * 256)
                  + ((size_t)(hp0 + wm) * 4) * 256;
    #pragma unroll
    for (int j = 0; j < 2; ++j) {
        const int ng = n0 + wn * 32 + j * 16 + lr;   // output channel-dim index e
        const int cc = ng >> 4;
        const int ph = (ng >> 2) & 3;
        const int pw = ng & 3;
        float* ybase = yb + ((size_t)cc * 256 + ph) * 256 + pw;
        #pragma unroll
        for (int i = 0; i < 4; ++i) {
            const int wpB = i * 16 + kg * 4;
            #pragma unroll
            for (int r = 0; r < 4; ++r)
                ybase[(size_t)(wpB + r) * 4] = acc[i][j][r];
        }
    }
}

extern "C" void kernel_launch(void* const* d_in, const int* in_sizes, int n_in,
                              void* d_out, int out_size, void* d_ws, size_t ws_size,
                              hipStream_t stream) {
    (void)in_sizes; (void)n_in; (void)out_size; (void)ws_size;
    const float* x  = (const float*)d_in[0];
    const float* Wm = (const float*)d_in[1];
    float* y = (float*)d_out;
    u32x4* Wp = (u32x4*)d_ws;   // needs 2 MB; harness workspace is larger
    wprep_kernel<<<dim3(512), dim3(256), 0, stream>>>(Wm, Wp);
    // 512 M-tiles x 16 N-tiles
    patchmix_kernel<<<dim3(8192), dim3(256), 0, stream>>>(x, Wp, y);
}

// Round 7
// 671.419 us; speedup vs baseline: 1.0577x; 1.0577x over previous
//
#include <hip/hip_runtime.h>
#include <stdint.h>

// Problem constants: x[16,64,256,256] fp32, W[1024,1024] fp32, P=4.
// GEMM view: C[m,n] = sum_k A[m,k] * W[n,k]
//   m = b*4096 + hp*64 + wp   (Hp=Wp=64)
//   k = c*16 + ph*4 + pw
//
// Round-7: ZERO-SYNC dataflow kernel. Evidence r1/r3/r5/r6: every
// barrier-locked LDS-roundtrip variant lands at 310-410 us with all pipes
// <20% busy -- the serialized pack->bar->ds_write->bar->ds_read->MFMA chain
// is the ceiling, at any occupancy (33-67%). Fix: no LDS, no barriers.
// Each wave owns a 32-row x 128-col output tile (acc[2][8] = 64 regs);
// the 4 waves of a block read DISJOINT A rows (r2's duplication bug fixed
// by wave-owns-rows decomposition), and B comes from the pre-packed bf16
// fragment table Wp (r5, verified): all 4 waves read the same B granules
// -> L1 hits (8 KB/iter << 32 KB L1).
// Pipelining: A prefetched 2 iterations deep (ping-pong aA/aB, ~2 iters of
// slack vs ~900cy HBM); B granule j for it+1 reloaded immediately after
// granule j of it is consumed (~1 iter slack vs ~200cy L2).

typedef float    f32x4  __attribute__((ext_vector_type(4)));
typedef uint32_t u32x4  __attribute__((ext_vector_type(4)));
typedef __bf16   bf16x8 __attribute__((ext_vector_type(8)));

// Truncate two f32 to bf16 and pack into one u32 (lo in low half).
__device__ __forceinline__ uint32_t pack2(float lo, float hi) {
    return __builtin_amdgcn_perm(__builtin_bit_cast(uint32_t, hi),
                                 __builtin_bit_cast(uint32_t, lo),
                                 0x07060302u);
}

// ---- W prep: W[n][k] fp32 -> Wp granule[kq][n] = 8 bf16 {k=kq*8..kq*8+7} ----
// 128k granules (kq 0..127, n 0..1023) = 2 MB, L2-resident.
__global__ __launch_bounds__(256)
void wprep_kernel(const float* __restrict__ Wm, u32x4* __restrict__ Wp) {
    const int t  = blockIdx.x * 256 + threadIdx.x;   // 0..131071
    if (t >= 128 * 1024) return;
    const int n  = t & 1023;                          // write-coalesced in n
    const int kq = t >> 10;                           // 0..127
    const float* src = Wm + (size_t)n * 1024 + (size_t)kq * 8;
    f32x4 lo = *(const f32x4*)(src);
    f32x4 hi = *(const f32x4*)(src + 4);
    Wp[(size_t)kq * 1024 + n] = (u32x4){ pack2(lo.x, lo.y), pack2(lo.z, lo.w),
                                         pack2(hi.x, hi.y), pack2(hi.z, hi.w) };
}

__global__ __launch_bounds__(256, 3)
void patchmix_kernel(const float* __restrict__ x,
                     const u32x4* __restrict__ Wp,
                     float* __restrict__ y) {
    // ---- XCD-aware block swizzle (T1): contiguous M-chunk per XCD, N fastest.
    const int bx  = blockIdx.x;
    const int xcd = bx & 7;
    const int jj  = bx >> 3;       // 0..511 within this XCD
    const int nt  = jj & 7;        // N-tile fastest -> A-strip L2 reuse
    const int mt  = xcd * 64 + (jj >> 3);   // 0..511
    const int bb  = mt >> 5;       // batch 0..15
    const int hp0 = (mt & 31) << 1;// first of 2 hp rows
    const int n0  = nt << 7;

    const int t    = threadIdx.x;
    const int lane = t & 63;
    const int wave = t >> 6;       // wave owns rows [wave*32, wave*32+32)

    const int kg  = lane >> 4;     // k-group 0..3
    const int lr  = lane & 15;

    // ---- A fragment geometry (direct from x, zero redundancy) ----
    // af[i]: lane holds A[m_local = wave*32 + i*16 + lr][k = kg*8 + jj2].
    // m_local<128: hpL = wave>>1, wp = (wave&1)*32 + i*16 + lr.
    // k: c = 2*it + (kg>>1), ph = 2*(kg&1) + {0,1}, pw = 0..3
    //   -> two f32x4 at +0 and +256 floats. 16 lanes x 16 B contiguous.
    const float* aBase = x + (size_t)bb * 4194304
                       + (size_t)(kg >> 1) * 65536
                       + ((size_t)(hp0 + (wave >> 1)) * 4 + 2 * (kg & 1)) * 256
                       + (size_t)((wave & 1) * 32 + lr) * 4;

    // ---- B fragment pointer: granule (it*4+kg)*1024 + (n0 + j*16 + lr) ----
    const u32x4* bFrag = Wp + (size_t)kg * 1024 + (size_t)(n0 + lr);

    f32x4 aA[2][2], aB[2][2];   // 2-deep A ping-pong (fp32 staging)
    auto loadA = [&](int it, f32x4 (&aU)[2][2]) {
        const float* a0 = aBase + (size_t)it * 131072;   // 2 channels/iter
        #pragma unroll
        for (int i = 0; i < 2; ++i) {
            aU[i][0] = *(const f32x4*)(a0 + i * 64);
            aU[i][1] = *(const f32x4*)(a0 + i * 64 + 256);
        }
    };

    u32x4 bR[8];
    auto loadB = [&](int it) {
        const u32x4* bi = bFrag + (size_t)it * 4096;
        #pragma unroll
        for (int j = 0; j < 8; ++j)
            bR[j] = bi[j * 16];
    };

    f32x4 acc[2][8];
    #pragma unroll
    for (int i = 0; i < 2; ++i)
        #pragma unroll
        for (int j = 0; j < 8; ++j)
            acc[i][j] = (f32x4){0.f, 0.f, 0.f, 0.f};

    // ---- prologue: A(0),A(1) staged; B(0) staged ----
    loadA(0, aA);
    loadB(0);
    loadA(1, aB);

    // body(it, aU): consumes A(it) from aU, refills aU with A(it+2),
    // MFMAs tile it while reloading bR granule-by-granule for it+1.
    auto body = [&](int it, f32x4 (&aU)[2][2]) {
        // 1. pack A(it) -> fragments (vmcnt wait: ~2 iters of slack)
        bf16x8 af[2];
        #pragma unroll
        for (int i = 0; i < 2; ++i) {
            u32x4 ap = (u32x4){ pack2(aU[i][0].x, aU[i][0].y), pack2(aU[i][0].z, aU[i][0].w),
                                pack2(aU[i][1].x, aU[i][1].y), pack2(aU[i][1].z, aU[i][1].w) };
            af[i] = __builtin_bit_cast(bf16x8, ap);
        }
        // 2. refill aU with A(it+2) immediately (max slack; clamp stays in-bounds)
        const int itA = (it + 2 < 32) ? (it + 2) : 31;
        loadA(itA, aU);
        // 3. MFMA j-loop; reload bR[j] for it+1 right after granule j consumed
        const int itB = (it + 1 < 32) ? (it + 1) : 31;
        const u32x4* bNext = bFrag + (size_t)itB * 4096;
        #pragma unroll
        for (int j = 0; j < 8; ++j) {
            bf16x8 bfj = __builtin_bit_cast(bf16x8, bR[j]);
            acc[0][j] = __builtin_amdgcn_mfma_f32_16x16x32_bf16(af[0], bfj, acc[0][j], 0, 0, 0);
            acc[1][j] = __builtin_amdgcn_mfma_f32_16x16x32_bf16(af[1], bfj, acc[1][j], 0, 0, 0);
            bR[j] = bNext[j * 16];
        }
    };

    #pragma unroll 1
    for (int it2 = 0; it2 < 16; ++it2) {
        body(2 * it2,     aA);
        body(2 * it2 + 1, aB);
    }

    // ---- epilogue: fold back to y[b][c][h][w] ----
    // D layout (m89): col n = lane&15, row m16 = (lane>>4)*4 + reg
    // m_local = wave*32 + i*16 + kg*4 + r -> hpL = wave>>1,
    // wp = (wave&1)*32 + i*16 + kg*4 + r
    float* yb = y + (size_t)bb * (64 * 256 * 256)
                  + ((size_t)(hp0 + (wave >> 1)) * 4) * 256;
    #pragma unroll
    for (int j = 0; j < 8; ++j) {
        const int ng = n0 + j * 16 + lr;   // output channel-dim index e
        const int cc = ng >> 4;
        const int ph = (ng >> 2) & 3;
        const int pw = ng & 3;
        float* ybase = yb + ((size_t)cc * 256 + ph) * 256 + pw;
        #pragma unroll
        for (int i = 0; i < 2; ++i) {
            const int wpB = (wave & 1) * 32 + i * 16 + kg * 4;
            #pragma unroll
            for (int r = 0; r < 4; ++r)
                ybase[(size_t)(wpB + r) * 4] = acc[i][j][r];
        }
    }
}

extern "C" void kernel_launch(void* const* d_in, const int* in_sizes, int n_in,
                              void* d_out, int out_size, void* d_ws, size_t ws_size,
                              hipStream_t stream) {
    (void)in_sizes; (void)n_in; (void)out_size; (void)ws_size;
    const float* x  = (const float*)d_in[0];
    const float* Wm = (const float*)d_in[1];
    float* y = (float*)d_out;
    u32x4* Wp = (u32x4*)d_ws;   // needs 2 MB; harness workspace is larger
    wprep_kernel<<<dim3(512), dim3(256), 0, stream>>>(Wm, Wp);
    // 512 M-tiles x 8 N-tiles
    patchmix_kernel<<<dim3(4096), dim3(256), 0, stream>>>(x, Wp, y);
}